// Round 8
// baseline (3631.047 us; speedup 1.0000x reference)
//
#include <hip/hip_runtime.h>
#include <cstdint>

#define B_    8
#define T_    16384
#define NA_   512
#define A_    512
#define NIT_  32
#define NCH_  256           // 64-sample chunks per row
#define EPSV  1e-8f
#define TPAD  16928         // padded per-batch length of xhh/xll (u32 each)

typedef unsigned long long u64;
typedef __attribute__((ext_vector_type(8))) short bf16x8;
typedef __attribute__((ext_vector_type(4))) float f32x4;

// ws float-offset layout (~11.6 MB total)
#define OFF_INV   0
#define OFF_SELA  512
#define OFF_SELT  768
#define OFF_SELV  1024
#define OFF_CM    1280        // u64[8*512*256] -> 2,097,152 floats
#define OFF_RMA   2098432     // u64[4096]
#define OFF_RMB   2106624     // u64[4096]
#define OFF_XRA   2114816     // f32[8*16384]
#define OFF_XRB   2245888     // f32[8*16384]
#define OFF_DPK   2376960     // u32[512*512]  d as (hi|lo<<16)
#define OFF_XHH   2639104     // u32[8*TPAD]   x as (hi,hi)   (initial conv only)
#define OFF_XLL   2774528     // u32[8*TPAD]   x as (lo,lo)
#define MAIN_NEED 2909952
// compact fallback layout
#define OFF_SXR   OFF_CM
#define OFF_SCAND (OFF_CM + 131072)
#define S_NEED    (OFF_SCAND + 16)

__device__ __forceinline__ unsigned int encf(float f) {
    unsigned int u = __float_as_uint(f);
    return (u & 0x80000000u) ? ~u : (u | 0x80000000u);
}
__device__ __forceinline__ float decf(unsigned int e) {
    unsigned int u = (e & 0x80000000u) ? (e & 0x7fffffffu) : ~e;
    return __uint_as_float(u);
}
__device__ __forceinline__ u64 umax64(u64 a, u64 b) { return a > b ? a : b; }
__device__ __forceinline__ u64 enc64(float v, unsigned int flat) {
    return (((u64)encf(v)) << 32) | (unsigned int)~flat;
}
__device__ __forceinline__ u64 shfl_xor_u64(u64 v, int mask) {
    unsigned int lo = (unsigned int)v, hi = (unsigned int)(v >> 32);
    lo = __shfl_xor(lo, mask, 64);
    hi = __shfl_xor(hi, mask, 64);
    return (((u64)hi) << 32) | lo;
}
__device__ __forceinline__ u64 shfl_down_u64(u64 v, int off) {
    unsigned int lo = (unsigned int)v, hi = (unsigned int)(v >> 32);
    lo = __shfl_down(lo, off, 64);
    hi = __shfl_down(hi, off, 64);
    return (((u64)hi) << 32) | lo;
}
// bf16 round-to-nearest-even from fp32
__device__ __forceinline__ unsigned short f2bf(float v) {
    unsigned int u = __float_as_uint(v);
    return (unsigned short)((u + 0x7fffu + ((u >> 16) & 1u)) >> 16);
}

// ---------------- inv[a] = 1/(||d_a||+eps) ----------------
__global__ __launch_bounds__(64) void k_inv(const float* __restrict__ d, float* __restrict__ inv) {
    const int a = blockIdx.x, lane = threadIdx.x;
    const float* row = d + a * A_;
    float s = 0.f;
    for (int i = lane; i < A_; i += 64) { float v = row[i]; s = fmaf(v, v, s); }
    #pragma unroll
    for (int o = 32; o > 0; o >>= 1) s += __shfl_down(s, o, 64);
    if (lane == 0) inv[a] = 1.0f / (sqrtf(s) + EPSV);
}

// ---------------- d -> packed (hi | lo<<16) ----------------
__global__ __launch_bounds__(256) void k_split_d(const float* __restrict__ d,
                                                 unsigned int* __restrict__ dpk) {
    int id = blockIdx.x * 256 + threadIdx.x;           // 262144
    float v = d[id];
    unsigned short hb = f2bf(v);
    unsigned short lb = f2bf(v - __uint_as_float((unsigned int)hb << 16));
    dpk[id] = (unsigned int)hb | ((unsigned int)lb << 16);
}

// ---------------- x -> duplicated-pair arrays (hi,hi) / (lo,lo), zero-padded ----------------
__global__ __launch_bounds__(256) void k_split_x(const float* __restrict__ x,
                                                 unsigned int* __restrict__ xhh,
                                                 unsigned int* __restrict__ xll) {
    int id = blockIdx.x * 256 + threadIdx.x;           // 8*TPAD = 135424
    int b = id / TPAD, i = id - b * TPAD;
    float v = (i < T_) ? x[b * T_ + i] : 0.f;
    unsigned short hb = f2bf(v);
    unsigned short lb = f2bf(v - __uint_as_float((unsigned int)hb << 16));
    xhh[id] = (unsigned int)hb * 0x10001u;
    xll[id] = (unsigned int)lb * 0x10001u;
}

// ---------------- initial full conv via MFMA (B operands from global) ----------------
__global__ __launch_bounds__(256) void k_conv(const unsigned int* __restrict__ dpk,
                                              const unsigned int* __restrict__ xhh,
                                              const unsigned int* __restrict__ xll,
                                              const float* __restrict__ inv,
                                              u64* __restrict__ cm) {
    const int tid = threadIdx.x;
    const int lane = tid & 63;
    const int c = lane & 15, q = lane >> 4;
    const int t0 = ((blockIdx.x << 2) + (tid >> 6)) << 6;
    const int a_base = blockIdx.y * 64;
    const int gb = blockIdx.z;

    const unsigned int* Ap[4];
    #pragma unroll
    for (int at = 0; at < 4; ++at)
        Ap[at] = dpk + ((a_base + 16 * at + c) << 9) + 4 * q;
    const unsigned int* Bh = xhh + gb * TPAD + t0 + c + 4 * q;
    const unsigned int* Bl = xll + gb * TPAD + t0 + c + 4 * q;

    f32x4 acc[4][4];
    const f32x4 zero = {0.f, 0.f, 0.f, 0.f};
    #pragma unroll
    for (int at = 0; at < 4; ++at)
        #pragma unroll
        for (int tt = 0; tt < 4; ++tt) acc[at][tt] = zero;

    for (int j0 = 0; j0 < A_; j0 += 16) {
        union { uint4 u; bf16x8 f; } Af[4];
        #pragma unroll
        for (int at = 0; at < 4; ++at) Af[at].u = *(const uint4*)(Ap[at] + j0);
        #pragma unroll
        for (int tt = 0; tt < 4; ++tt) {
            union { uint4 u; bf16x8 f; } bh, bl;
            const unsigned int* ph = Bh + 16 * tt + j0;
            const unsigned int* pl = Bl + 16 * tt + j0;
            bh.u.x = ph[0]; bh.u.y = ph[1]; bh.u.z = ph[2]; bh.u.w = ph[3];
            bl.u.x = pl[0]; bl.u.y = pl[1]; bl.u.z = pl[2]; bl.u.w = pl[3];
            #pragma unroll
            for (int at = 0; at < 4; ++at) {
                acc[at][tt] = __builtin_amdgcn_mfma_f32_16x16x32_bf16(Af[at].f, bh.f, acc[at][tt], 0, 0, 0);
                acc[at][tt] = __builtin_amdgcn_mfma_f32_16x16x32_bf16(Af[at].f, bl.f, acc[at][tt], 0, 0, 0);
            }
        }
    }

    const int ch = t0 >> 6;
    #pragma unroll
    for (int at = 0; at < 4; ++at) {
        #pragma unroll
        for (int r = 0; r < 4; ++r) {
            const int atom = a_base + 16 * at + 4 * q + r;
            const float iv = inv[atom];
            u64 m = 0ull;
            #pragma unroll
            for (int tt = 0; tt < 4; ++tt) {
                int t = t0 + 16 * tt + c;
                m = umax64(m, enc64(acc[at][tt][r] * iv, (unsigned int)(atom * T_ + t)));
            }
            m = umax64(m, shfl_xor_u64(m, 1));
            m = umax64(m, shfl_xor_u64(m, 2));
            m = umax64(m, shfl_xor_u64(m, 4));
            m = umax64(m, shfl_xor_u64(m, 8));
            if (c == 0)
                cm[((size_t)(gb * NA_ + atom) << 8) + ch] = m;
        }
    }
}

// ---------------- rm from cm (4 rows per block, wave per row) ----------------
__global__ __launch_bounds__(256) void k_tables(const u64* __restrict__ cm, u64* __restrict__ rm) {
    const int row = blockIdx.x * 4 + (threadIdx.x >> 6);
    const int lane = threadIdx.x & 63;
    const u64* p = cm + ((size_t)row << 8);
    u64 m = 0ull;
    #pragma unroll
    for (int k = 0; k < 4; ++k) m = umax64(m, p[lane + 64 * k]);
    #pragma unroll
    for (int o = 32; o > 0; o >>= 1) m = umax64(m, shfl_down_u64(m, o));
    if (lane == 0) rm[row] = m;
}

// ---------------- fused per-iteration kernel ----------------
// grid (8 atom-groups, 8 batches), 256 threads. Phases:
//   A: argmax from rmPrev (all blocks identical) -> selection
//   B: xr ping-pong slice copy with patch fused
//   C: stage patched window into LDS as 4 shift-copies of packed bf16 pairs
//   D: MFMA window conv (64 atoms x <=1088 t), rewrite cm chunks
//   E: rebuild rm for this block's 64 rows -> rmNext
__global__ __launch_bounds__(256) void k_it(const float* __restrict__ xrPrev,
                                            float* __restrict__ xrNext,
                                            const float* __restrict__ d,
                                            const float* __restrict__ inv,
                                            const unsigned int* __restrict__ dpk,
                                            u64* __restrict__ cm,
                                            const u64* __restrict__ rmPrev,
                                            u64* __restrict__ rmNext,
                                            int* __restrict__ selA,
                                            int* __restrict__ selT,
                                            float* __restrict__ selV,
                                            int it) {
    __shared__ u64 redU[256];
    __shared__ float xf[1604];          // patched fp32 window
    __shared__ uint4 s_hh[4][405];      // 4 shift-copies, packed (hi,hi); 1620 u32/row
    __shared__ uint4 s_ll[4][405];      // 4 shift-copies, packed (lo,lo)
    const int ag = blockIdx.x, b = blockIdx.y, tid = threadIdx.x;
    const int wave = tid >> 6, lane = tid & 63;
    const int c = lane & 15, q = lane >> 4;
    const int a0 = ag * 64;

    // ---- phase A ----
    const u64* rp = rmPrev + b * NA_;
    redU[tid] = umax64(rp[tid], rp[tid + 256]);
    __syncthreads();
    for (int s = 128; s > 0; s >>= 1) {
        if (tid < s) redU[tid] = umax64(redU[tid], redU[tid + s]);
        __syncthreads();
    }
    const u64 win = redU[0];
    __syncthreads();
    const unsigned int enc = (unsigned int)(win >> 32);
    const unsigned int flat = ~(unsigned int)win;
    const int asel = (int)(flat >> 14);
    const int tsel = (int)(flat & (T_ - 1));
    const float v = decf(enc);
    if (ag == 0 && tid == 0) {
        selA[it * B_ + b] = asel;
        selT[it * B_ + b] = tsel;
        selV[it * B_ + b] = v;
    }
    const int L = min(A_, (T_ - 1) - tsel);  // reference truncation quirk
    const float vv = v * inv[asel];

    // ---- phase B: xr ping-pong slice [ag*2048, +2048) ----
    #pragma unroll
    for (int k = 0; k < 8; ++k) {
        int t = ag * 2048 + k * 256 + tid;
        float xv = xrPrev[b * T_ + t];
        int o = t - tsel;
        if (L > 0 && o >= 0 && o < L) xv = fmaf(-vv, d[asel * A_ + o], xv);
        xrNext[b * T_ + t] = xv;
    }

    int ab = 0, nch = 0;
    if (L > 0) {
        const int tbeg = max(0, tsel - (A_ - 1));
        const int tend = tsel + L;               // <= 16383
        ab = tbeg & ~63;
        const int ae = (tend + 63) & ~63;        // <= T_
        const int W = ae - ab;                   // <= 1088
        nch = W >> 6;                            // <= 17
        const int NS = W + 512;                  // samples staged

        // ---- phase C: stage patched fp32, then 4 shift-copies of bf16 pairs ----
        for (int i = tid; i < NS + 3; i += 256) {
            int t = ab + i;
            float xv = (t < T_) ? xrPrev[b * T_ + t] : 0.f;
            int o = t - tsel;
            if (o >= 0 && o < L) xv = fmaf(-vv, d[asel * A_ + o], xv);
            xf[i] = xv;
        }
        __syncthreads();
        unsigned int* hw = (unsigned int*)s_hh;
        unsigned int* lw = (unsigned int*)s_ll;
        for (int i = tid; i < NS; i += 256) {
            #pragma unroll
            for (int s = 0; s < 4; ++s) {
                float xv = xf[i + s];
                unsigned short hb = f2bf(xv);
                unsigned short lb = f2bf(xv - __uint_as_float((unsigned int)hb << 16));
                hw[s * 1620 + i] = (unsigned int)hb * 0x10001u;
                lw[s * 1620 + i] = (unsigned int)lb * 0x10001u;
            }
        }
        __syncthreads();

        // ---- phase D: MFMA window conv; wave handles chunks wave, wave+4, ... ----
        const unsigned int* Ap[4];
        #pragma unroll
        for (int at = 0; at < 4; ++at)
            Ap[at] = dpk + ((a0 + 16 * at + c) << 9) + 4 * q;
        float ivv[4][4];
        #pragma unroll
        for (int at = 0; at < 4; ++at)
            #pragma unroll
            for (int r = 0; r < 4; ++r) ivv[at][r] = inv[a0 + 16 * at + 4 * q + r];
        const uint4* bhp = &s_hh[c & 3][(c >> 2) + q];
        const uint4* blp = &s_ll[c & 3][(c >> 2) + q];

        for (int ch = wave; ch < nch; ch += 4) {
            f32x4 acc[4][4];
            const f32x4 zero = {0.f, 0.f, 0.f, 0.f};
            #pragma unroll
            for (int at = 0; at < 4; ++at)
                #pragma unroll
                for (int tt = 0; tt < 4; ++tt) acc[at][tt] = zero;
            for (int j0 = 0; j0 < A_; j0 += 16) {
                union { uint4 u; bf16x8 f; } Af[4];
                #pragma unroll
                for (int at = 0; at < 4; ++at) Af[at].u = *(const uint4*)(Ap[at] + j0);
                #pragma unroll
                for (int tt = 0; tt < 4; ++tt) {
                    union { uint4 u; bf16x8 f; } bh, bl;
                    int i4 = 16 * ch + 4 * tt + (j0 >> 2);
                    bh.u = bhp[i4];
                    bl.u = blp[i4];
                    #pragma unroll
                    for (int at = 0; at < 4; ++at) {
                        acc[at][tt] = __builtin_amdgcn_mfma_f32_16x16x32_bf16(Af[at].f, bh.f, acc[at][tt], 0, 0, 0);
                        acc[at][tt] = __builtin_amdgcn_mfma_f32_16x16x32_bf16(Af[at].f, bl.f, acc[at][tt], 0, 0, 0);
                    }
                }
            }
            // epilogue: chunk maxima -> cm
            #pragma unroll
            for (int at = 0; at < 4; ++at) {
                #pragma unroll
                for (int r = 0; r < 4; ++r) {
                    const int atom = a0 + 16 * at + 4 * q + r;
                    u64 m = 0ull;
                    #pragma unroll
                    for (int tt = 0; tt < 4; ++tt) {
                        int t = ab + 64 * ch + 16 * tt + c;
                        m = umax64(m, enc64(acc[at][tt][r] * ivv[at][r],
                                            (unsigned int)(atom * T_ + t)));
                    }
                    m = umax64(m, shfl_xor_u64(m, 1));
                    m = umax64(m, shfl_xor_u64(m, 2));
                    m = umax64(m, shfl_xor_u64(m, 4));
                    m = umax64(m, shfl_xor_u64(m, 8));
                    if (c == 0)
                        cm[((size_t)(b * NA_ + atom) << 8) + (ab >> 6) + ch] = m;
                }
            }
        }
        __syncthreads();   // cm writes visible block-wide
    }

    // ---- phase E: rm for rows a0..a0+63 ----
    const int rl = tid >> 2, part = tid & 3;
    const u64* crow = cm + ((size_t)(b * NA_ + a0 + rl) << 8) + part * 64;
    u64 m = 0ull;
    for (int k = 0; k < 64; ++k) m = umax64(m, crow[k]);
    redU[tid] = m;
    __syncthreads();
    if (part == 0) {
        m = umax64(umax64(redU[tid], redU[tid + 1]), umax64(redU[tid + 2], redU[tid + 3]));
        rmNext[b * NA_ + a0 + rl] = m;
    }
}

// ---------------- slow fallback (tiny ws): residual-space recompute ----------------
__global__ void s_init(const float* __restrict__ x, float* __restrict__ xr,
                       u64* __restrict__ cand) {
    int i = blockIdx.x * 256 + threadIdx.x;
    if (i < B_ * T_) xr[i] = x[i];
    if (i < B_) cand[i] = 0ull;
}
__global__ __launch_bounds__(256) void s_scan(const float* __restrict__ xr,
                                              const float* __restrict__ d,
                                              const float* __restrict__ inv,
                                              u64* __restrict__ cand) {
    __shared__ float dLs[A_];
    __shared__ u64 redU[256];
    const int aB = blockIdx.x, b = blockIdx.y, tid = threadIdx.x;
    const float iv = inv[aB];
    for (int i = tid; i < A_; i += 256) dLs[i] = d[aB * A_ + i] * iv;
    __syncthreads();
    const float* xb = xr + b * T_;
    u64 best = 0ull;
    for (int t = tid; t < T_; t += 256) {
        float acc = 0.f;
        int lim = min(A_, T_ - t);
        for (int i = 0; i < lim; ++i) acc = fmaf(dLs[i], xb[t + i], acc);
        best = umax64(best, enc64(acc, (unsigned int)(aB * T_ + t)));
    }
    redU[tid] = best;
    __syncthreads();
    for (int s = 128; s > 0; s >>= 1) {
        if (tid < s) redU[tid] = umax64(redU[tid], redU[tid + s]);
        __syncthreads();
    }
    if (tid == 0) atomicMax(&cand[b], redU[0]);
}
__global__ void s_apply(float* __restrict__ xr, const float* __restrict__ d,
                        const float* __restrict__ inv, u64* __restrict__ cand,
                        int* selA, int* selT, float* selV, int it) {
    const int b = blockIdx.x, tid = threadIdx.x;
    u64 win = cand[b];
    unsigned int enc = (unsigned int)(win >> 32);
    unsigned int flat = ~(unsigned int)win;
    int a = (int)(flat >> 14), t = (int)(flat & (T_ - 1));
    float v = decf(enc);
    if (tid == 0) { selA[it * B_ + b] = a; selT[it * B_ + b] = t; selV[it * B_ + b] = v; }
    float vvl = v * inv[a];
    int L = min(A_, (T_ - 1) - t);
    for (int o = tid; o < L; o += 256) xr[b * T_ + t + o] -= vvl * d[a * A_ + o];
    if (tid == 0) cand[b] = 0ull;
}

// ---------------- reconstruct (residual, recon) from selections ----------------
__global__ __launch_bounds__(256) void k_final(const float* __restrict__ x,
                                               const float* __restrict__ d,
                                               const int* __restrict__ selA,
                                               const int* __restrict__ selT,
                                               const float* __restrict__ selV,
                                               const float* __restrict__ inv,
                                               float* __restrict__ out) {
    const int gid = blockIdx.x * 256 + threadIdx.x;
    const int b = gid >> 14;
    const int t = gid & (T_ - 1);
    float r = x[gid];
    float rec = 0.f;
    for (int k = 0; k < NIT_; ++k) {           // sequential: reference fp order
        int a  = selA[k * B_ + b];
        int ts = selT[k * B_ + b];
        float vvl = selV[k * B_ + b] * inv[a];
        int o = t - ts;
        int L = min(A_, (T_ - 1) - ts);
        if (o >= 0 && o < L) {
            float c = vvl * d[a * A_ + o];
            r -= c;
            rec += c;
        }
    }
    out[gid] = r;
    out[B_ * T_ + gid] = rec;
}

extern "C" void kernel_launch(void* const* d_in, const int* in_sizes, int n_in,
                              void* d_out, int out_size, void* d_ws, size_t ws_size,
                              hipStream_t stream) {
    const float* x = (const float*)d_in[0];
    const float* d = (const float*)d_in[1];
    float* out = (float*)d_out;
    float* ws = (float*)d_ws;
    const size_t wsf = ws_size / sizeof(float);

    float* inv  = ws + OFF_INV;
    int*   selA = (int*)(ws + OFF_SELA);
    int*   selT = (int*)(ws + OFF_SELT);
    float* selV = ws + OFF_SELV;

    if (wsf < (size_t)S_NEED) return;   // hopeless

    k_inv<<<dim3(NA_), dim3(64), 0, stream>>>(d, inv);

    if (wsf >= (size_t)MAIN_NEED) {
        u64* cm  = (u64*)(ws + OFF_CM);
        u64* rmA = (u64*)(ws + OFF_RMA);
        u64* rmB = (u64*)(ws + OFF_RMB);
        float* xrA = ws + OFF_XRA;
        float* xrB = ws + OFF_XRB;
        unsigned int* dpk = (unsigned int*)(ws + OFF_DPK);
        unsigned int* xhh = (unsigned int*)(ws + OFF_XHH);
        unsigned int* xll = (unsigned int*)(ws + OFF_XLL);

        k_split_d<<<dim3(NA_ * A_ / 256), dim3(256), 0, stream>>>(d, dpk);
        k_split_x<<<dim3(B_ * TPAD / 256), dim3(256), 0, stream>>>(x, xhh, xll);
        hipMemcpyAsync(xrA, x, (size_t)B_ * T_ * sizeof(float),
                       hipMemcpyDeviceToDevice, stream);
        k_conv<<<dim3(64, 8, B_), dim3(256), 0, stream>>>(dpk, xhh, xll, inv, cm);
        k_tables<<<dim3(B_ * NA_ / 4), dim3(256), 0, stream>>>(cm, rmA);
        for (int it = 0; it < NIT_; ++it) {
            const float* xp = (it & 1) ? xrB : xrA;
            float*       xn = (it & 1) ? xrA : xrB;
            const u64*   ro = (it & 1) ? rmB : rmA;
            u64*         rn = (it & 1) ? rmA : rmB;
            k_it<<<dim3(8, B_), dim3(256), 0, stream>>>(xp, xn, d, inv, dpk, cm, ro, rn,
                                                        selA, selT, selV, it);
        }
    } else {
        float* xr = ws + OFF_SXR;
        u64* cand = (u64*)(ws + OFF_SCAND);
        s_init<<<dim3((B_ * T_ + 255) / 256), dim3(256), 0, stream>>>(x, xr, cand);
        for (int it = 0; it < NIT_; ++it) {
            s_scan<<<dim3(NA_, B_), dim3(256), 0, stream>>>(xr, d, inv, cand);
            s_apply<<<dim3(B_), dim3(256), 0, stream>>>(xr, d, inv, cand, selA, selT, selV, it);
        }
    }

    k_final<<<dim3(B_ * T_ / 256), dim3(256), 0, stream>>>(x, d, selA, selT, selV, inv, out);
}

// Round 9
// 3444.534 us; speedup vs baseline: 1.0541x; 1.0541x over previous
//
#include <hip/hip_runtime.h>
#include <cstdint>

#define B_    8
#define T_    16384
#define NA_   512
#define A_    512
#define NIT_  32
#define NCH_  256           // 64-sample chunks per row
#define EPSV  1e-8f
#define TPAD  16928         // padded per-batch length of shifted packed x (u32)

typedef unsigned long long u64;
typedef __attribute__((ext_vector_type(8))) short bf16x8;
typedef __attribute__((ext_vector_type(4))) float f32x4;

// ws float-offset layout (~14.9 MB total)
#define OFF_INV   0
#define OFF_SELA  512
#define OFF_SELT  768
#define OFF_SELV  1024
#define OFF_CM    1280        // u64[8*512*256] -> 2,097,152 floats
#define OFF_RMA   2098432     // u64[4096]
#define OFF_RMB   2106624     // u64[4096]
#define OFF_XRA   2114816     // f32[8*16384]
#define OFF_XRB   2245888     // f32[8*16384]
#define OFF_DPK   2376960     // u32[512*512]   d as (hi|lo<<16)
#define OFF_XS4H  2639104     // u32[4*8*TPAD]  x (hi,hi), 4 shifts
#define OFF_XS4L  3180800     // u32[4*8*TPAD]  x (lo,lo), 4 shifts
#define MAIN_NEED 3722496
// compact fallback layout
#define OFF_SXR   OFF_CM
#define OFF_SCAND (OFF_CM + 131072)
#define S_NEED    (OFF_SCAND + 16)

__device__ __forceinline__ unsigned int encf(float f) {
    unsigned int u = __float_as_uint(f);
    return (u & 0x80000000u) ? ~u : (u | 0x80000000u);
}
__device__ __forceinline__ float decf(unsigned int e) {
    unsigned int u = (e & 0x80000000u) ? (e & 0x7fffffffu) : ~e;
    return __uint_as_float(u);
}
__device__ __forceinline__ u64 umax64(u64 a, u64 b) { return a > b ? a : b; }
__device__ __forceinline__ u64 enc64(float v, unsigned int flat) {
    return (((u64)encf(v)) << 32) | (unsigned int)~flat;
}
__device__ __forceinline__ u64 shfl_xor_u64(u64 v, int mask) {
    unsigned int lo = (unsigned int)v, hi = (unsigned int)(v >> 32);
    lo = __shfl_xor(lo, mask, 64);
    hi = __shfl_xor(hi, mask, 64);
    return (((u64)hi) << 32) | lo;
}
__device__ __forceinline__ u64 shfl_down_u64(u64 v, int off) {
    unsigned int lo = (unsigned int)v, hi = (unsigned int)(v >> 32);
    lo = __shfl_down(lo, off, 64);
    hi = __shfl_down(hi, off, 64);
    return (((u64)hi) << 32) | lo;
}
// bf16 round-to-nearest-even from fp32
__device__ __forceinline__ unsigned short f2bf(float v) {
    unsigned int u = __float_as_uint(v);
    return (unsigned short)((u + 0x7fffu + ((u >> 16) & 1u)) >> 16);
}

// ---------------- inv[a] = 1/(||d_a||+eps) ----------------
__global__ __launch_bounds__(64) void k_inv(const float* __restrict__ d, float* __restrict__ inv) {
    const int a = blockIdx.x, lane = threadIdx.x;
    const float* row = d + a * A_;
    float s = 0.f;
    for (int i = lane; i < A_; i += 64) { float v = row[i]; s = fmaf(v, v, s); }
    #pragma unroll
    for (int o = 32; o > 0; o >>= 1) s += __shfl_down(s, o, 64);
    if (lane == 0) inv[a] = 1.0f / (sqrtf(s) + EPSV);
}

// ---------------- d -> packed (hi | lo<<16) ----------------
__global__ __launch_bounds__(256) void k_split_d(const float* __restrict__ d,
                                                 unsigned int* __restrict__ dpk) {
    int id = blockIdx.x * 256 + threadIdx.x;           // 262144
    float v = d[id];
    unsigned short hb = f2bf(v);
    unsigned short lb = f2bf(v - __uint_as_float((unsigned int)hb << 16));
    dpk[id] = (unsigned int)hb | ((unsigned int)lb << 16);
}

// ---------------- x -> 4 shifted copies of (hi,hi) / (lo,lo), zero-padded ----------------
// xs[s][b][p] holds sample x[b][p+s]; makes every misaligned window a 16B-aligned read.
__global__ __launch_bounds__(256) void k_split_x4(const float* __restrict__ x,
                                                  unsigned int* __restrict__ xs4h,
                                                  unsigned int* __restrict__ xs4l) {
    int id = blockIdx.x * 256 + threadIdx.x;           // 4*B_*TPAD = 541696
    if (id >= 4 * B_ * TPAD) return;
    int s = id / (B_ * TPAD);
    int rem = id - s * (B_ * TPAD);
    int b = rem / TPAD, p = rem - b * TPAD;
    int e = p + s;
    float v = (e < T_) ? x[b * T_ + e] : 0.f;
    unsigned short hb = f2bf(v);
    unsigned short lb = f2bf(v - __uint_as_float((unsigned int)hb << 16));
    xs4h[id] = (unsigned int)hb * 0x10001u;
    xs4l[id] = (unsigned int)lb * 0x10001u;
}

// ---------------- initial full conv via MFMA (aligned b128 B-loads) ----------------
__global__ __launch_bounds__(256) void k_conv(const unsigned int* __restrict__ dpk,
                                              const unsigned int* __restrict__ xs4h,
                                              const unsigned int* __restrict__ xs4l,
                                              const float* __restrict__ inv,
                                              u64* __restrict__ cm) {
    const int tid = threadIdx.x;
    const int lane = tid & 63;
    const int c = lane & 15, q = lane >> 4;
    const int t0 = ((blockIdx.x << 2) + (tid >> 6)) << 6;
    const int a_base = blockIdx.y * 64;
    const int gb = blockIdx.z;

    const unsigned int* Ap[4];
    #pragma unroll
    for (int at = 0; at < 4; ++at)
        Ap[at] = dpk + ((a_base + 16 * at + c) << 9) + 4 * q;
    const size_t boff = (size_t)((c & 3) * B_ + gb) * TPAD + t0 + (c & ~3) + 4 * q;
    const uint4* Bh4 = (const uint4*)(xs4h + boff);
    const uint4* Bl4 = (const uint4*)(xs4l + boff);

    f32x4 acc[4][4];
    const f32x4 zero = {0.f, 0.f, 0.f, 0.f};
    #pragma unroll
    for (int at = 0; at < 4; ++at)
        #pragma unroll
        for (int tt = 0; tt < 4; ++tt) acc[at][tt] = zero;

    for (int j0 = 0; j0 < A_; j0 += 16) {
        union { uint4 u; bf16x8 f; } Af[4], bh[4], bl[4];
        #pragma unroll
        for (int at = 0; at < 4; ++at) Af[at].u = *(const uint4*)(Ap[at] + j0);
        #pragma unroll
        for (int tt = 0; tt < 4; ++tt) {
            bh[tt].u = Bh4[(j0 >> 2) + 4 * tt];
            bl[tt].u = Bl4[(j0 >> 2) + 4 * tt];
        }
        // 16 independent hi-MFMAs, then 16 lo (dep gap = 16 instrs)
        #pragma unroll
        for (int tt = 0; tt < 4; ++tt)
            #pragma unroll
            for (int at = 0; at < 4; ++at)
                acc[at][tt] = __builtin_amdgcn_mfma_f32_16x16x32_bf16(Af[at].f, bh[tt].f, acc[at][tt], 0, 0, 0);
        #pragma unroll
        for (int tt = 0; tt < 4; ++tt)
            #pragma unroll
            for (int at = 0; at < 4; ++at)
                acc[at][tt] = __builtin_amdgcn_mfma_f32_16x16x32_bf16(Af[at].f, bl[tt].f, acc[at][tt], 0, 0, 0);
    }

    const int ch = t0 >> 6;
    #pragma unroll
    for (int at = 0; at < 4; ++at) {
        #pragma unroll
        for (int r = 0; r < 4; ++r) {
            const int atom = a_base + 16 * at + 4 * q + r;
            const float iv = inv[atom];
            u64 m = 0ull;
            #pragma unroll
            for (int tt = 0; tt < 4; ++tt) {
                int t = t0 + 16 * tt + c;
                m = umax64(m, enc64(acc[at][tt][r] * iv, (unsigned int)(atom * T_ + t)));
            }
            m = umax64(m, shfl_xor_u64(m, 1));
            m = umax64(m, shfl_xor_u64(m, 2));
            m = umax64(m, shfl_xor_u64(m, 4));
            m = umax64(m, shfl_xor_u64(m, 8));
            if (c == 0)
                cm[((size_t)(gb * NA_ + atom) << 8) + ch] = m;
        }
    }
}

// ---------------- rm from cm (4 rows per block, wave per row) ----------------
__global__ __launch_bounds__(256) void k_tables(const u64* __restrict__ cm, u64* __restrict__ rm) {
    const int row = blockIdx.x * 4 + (threadIdx.x >> 6);
    const int lane = threadIdx.x & 63;
    const u64* p = cm + ((size_t)row << 8);
    u64 m = 0ull;
    #pragma unroll
    for (int k = 0; k < 4; ++k) m = umax64(m, p[lane + 64 * k]);
    #pragma unroll
    for (int o = 32; o > 0; o >>= 1) m = umax64(m, shfl_down_u64(m, o));
    if (lane == 0) rm[row] = m;
}

// ---------------- fused per-iteration kernel (512 threads, 8 waves) ----------------
// grid (8 atom-groups, 8 batches). Phases:
//   A: argmax from rmPrev (all blocks identical) -> selection
//   B: xr ping-pong slice copy with patch fused
//   C: stage patched window into LDS as 4 shift-copies of packed bf16 pairs
//   D: MFMA window conv (64 atoms x <=1088 t), rewrite cm chunks
//   E: rebuild rm for this block's 64 rows (lane-coalesced) -> rmNext
__global__ __launch_bounds__(512) void k_it(const float* __restrict__ xrPrev,
                                            float* __restrict__ xrNext,
                                            const float* __restrict__ d,
                                            const float* __restrict__ inv,
                                            const unsigned int* __restrict__ dpk,
                                            u64* __restrict__ cm,
                                            const u64* __restrict__ rmPrev,
                                            u64* __restrict__ rmNext,
                                            int* __restrict__ selA,
                                            int* __restrict__ selT,
                                            float* __restrict__ selV,
                                            int it) {
    __shared__ u64 redU[512];
    __shared__ float xf[1604];          // patched fp32 window
    __shared__ uint4 s_hh[4][405];      // 4 shift-copies, packed (hi,hi); 1620 u32/row
    __shared__ uint4 s_ll[4][405];      // 4 shift-copies, packed (lo,lo)
    const int ag = blockIdx.x, b = blockIdx.y, tid = threadIdx.x;
    const int wave = tid >> 6, lane = tid & 63;
    const int c = lane & 15, q = lane >> 4;
    const int a0 = ag * 64;

    // ---- phase A ----
    const u64* rp = rmPrev + b * NA_;
    redU[tid] = rp[tid];
    __syncthreads();
    for (int s = 256; s > 0; s >>= 1) {
        if (tid < s) redU[tid] = umax64(redU[tid], redU[tid + s]);
        __syncthreads();
    }
    const u64 win = redU[0];
    __syncthreads();
    const unsigned int enc = (unsigned int)(win >> 32);
    const unsigned int flat = ~(unsigned int)win;
    const int asel = (int)(flat >> 14);
    const int tsel = (int)(flat & (T_ - 1));
    const float v = decf(enc);
    if (ag == 0 && tid == 0) {
        selA[it * B_ + b] = asel;
        selT[it * B_ + b] = tsel;
        selV[it * B_ + b] = v;
    }
    const int L = min(A_, (T_ - 1) - tsel);  // reference truncation quirk
    const float vv = v * inv[asel];

    // ---- phase B: xr ping-pong slice [ag*2048, +2048) ----
    #pragma unroll
    for (int k = 0; k < 4; ++k) {
        int t = ag * 2048 + k * 512 + tid;
        float xv = xrPrev[b * T_ + t];
        int o = t - tsel;
        if (L > 0 && o >= 0 && o < L) xv = fmaf(-vv, d[asel * A_ + o], xv);
        xrNext[b * T_ + t] = xv;
    }

    int ab = 0, nch = 0;
    if (L > 0) {
        const int tbeg = max(0, tsel - (A_ - 1));
        const int tend = tsel + L;               // <= 16383
        ab = tbeg & ~63;
        const int ae = (tend + 63) & ~63;        // <= T_
        const int W = ae - ab;                   // <= 1088
        nch = W >> 6;                            // <= 17
        const int NS = W + 512;                  // samples staged

        // ---- phase C: stage patched fp32, then 4 shift-copies of bf16 pairs ----
        for (int i = tid; i < NS + 3; i += 512) {
            int t = ab + i;
            float xv = (t < T_) ? xrPrev[b * T_ + t] : 0.f;
            int o = t - tsel;
            if (o >= 0 && o < L) xv = fmaf(-vv, d[asel * A_ + o], xv);
            xf[i] = xv;
        }
        __syncthreads();
        unsigned int* hw = (unsigned int*)s_hh;
        unsigned int* lw = (unsigned int*)s_ll;
        for (int i = tid; i < NS; i += 512) {
            #pragma unroll
            for (int s = 0; s < 4; ++s) {
                float xv = xf[i + s];
                unsigned short hb = f2bf(xv);
                unsigned short lb = f2bf(xv - __uint_as_float((unsigned int)hb << 16));
                hw[s * 1620 + i] = (unsigned int)hb * 0x10001u;
                lw[s * 1620 + i] = (unsigned int)lb * 0x10001u;
            }
        }
        __syncthreads();

        // ---- phase D: MFMA window conv; wave handles chunks wave, wave+8, ... ----
        const unsigned int* Ap[4];
        #pragma unroll
        for (int at = 0; at < 4; ++at)
            Ap[at] = dpk + ((a0 + 16 * at + c) << 9) + 4 * q;
        float ivv[4][4];
        #pragma unroll
        for (int at = 0; at < 4; ++at)
            #pragma unroll
            for (int r = 0; r < 4; ++r) ivv[at][r] = inv[a0 + 16 * at + 4 * q + r];
        const uint4* bhp = &s_hh[c & 3][(c >> 2) + q];
        const uint4* blp = &s_ll[c & 3][(c >> 2) + q];

        for (int ch = wave; ch < nch; ch += 8) {
            f32x4 acc[4][4];
            const f32x4 zero = {0.f, 0.f, 0.f, 0.f};
            #pragma unroll
            for (int at = 0; at < 4; ++at)
                #pragma unroll
                for (int tt = 0; tt < 4; ++tt) acc[at][tt] = zero;
            for (int j0 = 0; j0 < A_; j0 += 16) {
                union { uint4 u; bf16x8 f; } Af[4], bh[4], bl[4];
                #pragma unroll
                for (int at = 0; at < 4; ++at) Af[at].u = *(const uint4*)(Ap[at] + j0);
                #pragma unroll
                for (int tt = 0; tt < 4; ++tt) {
                    int i4 = 16 * ch + 4 * tt + (j0 >> 2);
                    bh[tt].u = bhp[i4];
                    bl[tt].u = blp[i4];
                }
                #pragma unroll
                for (int tt = 0; tt < 4; ++tt)
                    #pragma unroll
                    for (int at = 0; at < 4; ++at)
                        acc[at][tt] = __builtin_amdgcn_mfma_f32_16x16x32_bf16(Af[at].f, bh[tt].f, acc[at][tt], 0, 0, 0);
                #pragma unroll
                for (int tt = 0; tt < 4; ++tt)
                    #pragma unroll
                    for (int at = 0; at < 4; ++at)
                        acc[at][tt] = __builtin_amdgcn_mfma_f32_16x16x32_bf16(Af[at].f, bl[tt].f, acc[at][tt], 0, 0, 0);
            }
            // epilogue: chunk maxima -> cm
            #pragma unroll
            for (int at = 0; at < 4; ++at) {
                #pragma unroll
                for (int r = 0; r < 4; ++r) {
                    const int atom = a0 + 16 * at + 4 * q + r;
                    u64 m = 0ull;
                    #pragma unroll
                    for (int tt = 0; tt < 4; ++tt) {
                        int t = ab + 64 * ch + 16 * tt + c;
                        m = umax64(m, enc64(acc[at][tt][r] * ivv[at][r],
                                            (unsigned int)(atom * T_ + t)));
                    }
                    m = umax64(m, shfl_xor_u64(m, 1));
                    m = umax64(m, shfl_xor_u64(m, 2));
                    m = umax64(m, shfl_xor_u64(m, 4));
                    m = umax64(m, shfl_xor_u64(m, 8));
                    if (c == 0)
                        cm[((size_t)(b * NA_ + atom) << 8) + (ab >> 6) + ch] = m;
                }
            }
        }
        __syncthreads();   // cm writes visible block-wide
    }

    // ---- phase E: rm for rows a0..a0+63, lane-coalesced, wave per row ----
    #pragma unroll
    for (int r8 = 0; r8 < 8; ++r8) {
        const int row = a0 + wave * 8 + r8;
        const u64* p = cm + ((size_t)(b * NA_ + row) << 8);
        u64 m = umax64(umax64(p[lane], p[lane + 64]),
                       umax64(p[lane + 128], p[lane + 192]));
        #pragma unroll
        for (int o = 32; o > 0; o >>= 1) m = umax64(m, shfl_down_u64(m, o));
        if (lane == 0) rmNext[b * NA_ + row] = m;
    }
}

// ---------------- slow fallback (tiny ws): residual-space recompute ----------------
__global__ void s_init(const float* __restrict__ x, float* __restrict__ xr,
                       u64* __restrict__ cand) {
    int i = blockIdx.x * 256 + threadIdx.x;
    if (i < B_ * T_) xr[i] = x[i];
    if (i < B_) cand[i] = 0ull;
}
__global__ __launch_bounds__(256) void s_scan(const float* __restrict__ xr,
                                              const float* __restrict__ d,
                                              const float* __restrict__ inv,
                                              u64* __restrict__ cand) {
    __shared__ float dLs[A_];
    __shared__ u64 redU[256];
    const int aB = blockIdx.x, b = blockIdx.y, tid = threadIdx.x;
    const float iv = inv[aB];
    for (int i = tid; i < A_; i += 256) dLs[i] = d[aB * A_ + i] * iv;
    __syncthreads();
    const float* xb = xr + b * T_;
    u64 best = 0ull;
    for (int t = tid; t < T_; t += 256) {
        float acc = 0.f;
        int lim = min(A_, T_ - t);
        for (int i = 0; i < lim; ++i) acc = fmaf(dLs[i], xb[t + i], acc);
        best = umax64(best, enc64(acc, (unsigned int)(aB * T_ + t)));
    }
    redU[tid] = best;
    __syncthreads();
    for (int s = 128; s > 0; s >>= 1) {
        if (tid < s) redU[tid] = umax64(redU[tid], redU[tid + s]);
        __syncthreads();
    }
    if (tid == 0) atomicMax(&cand[b], redU[0]);
}
__global__ void s_apply(float* __restrict__ xr, const float* __restrict__ d,
                        const float* __restrict__ inv, u64* __restrict__ cand,
                        int* selA, int* selT, float* selV, int it) {
    const int b = blockIdx.x, tid = threadIdx.x;
    u64 win = cand[b];
    unsigned int enc = (unsigned int)(win >> 32);
    unsigned int flat = ~(unsigned int)win;
    int a = (int)(flat >> 14), t = (int)(flat & (T_ - 1));
    float v = decf(enc);
    if (tid == 0) { selA[it * B_ + b] = a; selT[it * B_ + b] = t; selV[it * B_ + b] = v; }
    float vvl = v * inv[a];
    int L = min(A_, (T_ - 1) - t);
    for (int o = tid; o < L; o += 256) xr[b * T_ + t + o] -= vvl * d[a * A_ + o];
    if (tid == 0) cand[b] = 0ull;
}

// ---------------- reconstruct (residual, recon) from selections ----------------
__global__ __launch_bounds__(256) void k_final(const float* __restrict__ x,
                                               const float* __restrict__ d,
                                               const int* __restrict__ selA,
                                               const int* __restrict__ selT,
                                               const float* __restrict__ selV,
                                               const float* __restrict__ inv,
                                               float* __restrict__ out) {
    const int gid = blockIdx.x * 256 + threadIdx.x;
    const int b = gid >> 14;
    const int t = gid & (T_ - 1);
    float r = x[gid];
    float rec = 0.f;
    for (int k = 0; k < NIT_; ++k) {           // sequential: reference fp order
        int a  = selA[k * B_ + b];
        int ts = selT[k * B_ + b];
        float vvl = selV[k * B_ + b] * inv[a];
        int o = t - ts;
        int L = min(A_, (T_ - 1) - ts);
        if (o >= 0 && o < L) {
            float c = vvl * d[a * A_ + o];
            r -= c;
            rec += c;
        }
    }
    out[gid] = r;
    out[B_ * T_ + gid] = rec;
}

extern "C" void kernel_launch(void* const* d_in, const int* in_sizes, int n_in,
                              void* d_out, int out_size, void* d_ws, size_t ws_size,
                              hipStream_t stream) {
    const float* x = (const float*)d_in[0];
    const float* d = (const float*)d_in[1];
    float* out = (float*)d_out;
    float* ws = (float*)d_ws;
    const size_t wsf = ws_size / sizeof(float);

    float* inv  = ws + OFF_INV;
    int*   selA = (int*)(ws + OFF_SELA);
    int*   selT = (int*)(ws + OFF_SELT);
    float* selV = ws + OFF_SELV;

    if (wsf < (size_t)S_NEED) return;   // hopeless

    k_inv<<<dim3(NA_), dim3(64), 0, stream>>>(d, inv);

    if (wsf >= (size_t)MAIN_NEED) {
        u64* cm  = (u64*)(ws + OFF_CM);
        u64* rmA = (u64*)(ws + OFF_RMA);
        u64* rmB = (u64*)(ws + OFF_RMB);
        float* xrA = ws + OFF_XRA;
        float* xrB = ws + OFF_XRB;
        unsigned int* dpk  = (unsigned int*)(ws + OFF_DPK);
        unsigned int* xs4h = (unsigned int*)(ws + OFF_XS4H);
        unsigned int* xs4l = (unsigned int*)(ws + OFF_XS4L);

        k_split_d<<<dim3(NA_ * A_ / 256), dim3(256), 0, stream>>>(d, dpk);
        k_split_x4<<<dim3((4 * B_ * TPAD + 255) / 256), dim3(256), 0, stream>>>(x, xs4h, xs4l);
        hipMemcpyAsync(xrA, x, (size_t)B_ * T_ * sizeof(float),
                       hipMemcpyDeviceToDevice, stream);
        k_conv<<<dim3(64, 8, B_), dim3(256), 0, stream>>>(dpk, xs4h, xs4l, inv, cm);
        k_tables<<<dim3(B_ * NA_ / 4), dim3(256), 0, stream>>>(cm, rmA);
        for (int it = 0; it < NIT_; ++it) {
            const float* xp = (it & 1) ? xrB : xrA;
            float*       xn = (it & 1) ? xrA : xrB;
            const u64*   ro = (it & 1) ? rmB : rmA;
            u64*         rn = (it & 1) ? rmA : rmB;
            k_it<<<dim3(8, B_), dim3(512), 0, stream>>>(xp, xn, d, inv, dpk, cm, ro, rn,
                                                        selA, selT, selV, it);
        }
    } else {
        float* xr = ws + OFF_SXR;
        u64* cand = (u64*)(ws + OFF_SCAND);
        s_init<<<dim3((B_ * T_ + 255) / 256), dim3(256), 0, stream>>>(x, xr, cand);
        for (int it = 0; it < NIT_; ++it) {
            s_scan<<<dim3(NA_, B_), dim3(256), 0, stream>>>(xr, d, inv, cand);
            s_apply<<<dim3(B_), dim3(256), 0, stream>>>(xr, d, inv, cand, selA, selT, selV, it);
        }
    }

    k_final<<<dim3(B_ * T_ / 256), dim3(256), 0, stream>>>(x, d, selA, selT, selV, inv, out);
}